// Round 4
// baseline (67.215 us; speedup 1.0000x reference)
//
#include <hip/hip_runtime.h>
#include <hip/hip_bf16.h>

typedef float  f32x4 __attribute__((ext_vector_type(4)));
typedef short  s16x8 __attribute__((ext_vector_type(8)));
typedef __bf16 b16x8 __attribute__((ext_vector_type(8)));

#define NROWS 8192

__device__ __forceinline__ f32x4 mfma_bf16(s16x8 a, s16x8 b, f32x4 c) {
    return __builtin_amdgcn_mfma_f32_16x16x32_bf16(
        __builtin_bit_cast(b16x8, a), __builtin_bit_cast(b16x8, b), c, 0, 0, 0);
}

__device__ __forceinline__ short f2b(float f) {
    return __builtin_bit_cast(short, (__bf16)f);
}

__device__ __forceinline__ s16x8 pack8(f32x4 a, f32x4 b) {
    s16x8 r;
    r[0] = f2b(a[0]); r[1] = f2b(a[1]); r[2] = f2b(a[2]); r[3] = f2b(a[3]);
    r[4] = f2b(b[0]); r[5] = f2b(b[1]); r[6] = f2b(b[2]); r[7] = f2b(b[3]);
    return r;
}

// kappa k-map fragment loader: slot s<4 <- col cb + g*4 + s ; slot s>=4 <- col cb + 16 + g*4 + (s-4)
// Across the 4 g-lanes of a fixed c, each f32x4 load covers 64 contiguous bytes.
__device__ __forceinline__ s16x8 load_frag_k(const float* __restrict__ mat, int row, int cb, int g) {
    const float* p = mat + row * 64 + cb + g * 4;
    return pack8(*reinterpret_cast<const f32x4*>(p), *reinterpret_cast<const f32x4*>(p + 16));
}

// Per row n: Out = W1 (64x64) * X (64x64) * W2^T (64x64), all MFMA k-maps use kappa.
// Stage 1: T = X @ W2^T.  acc1[mt][nt]: lane(c,g) holds T[mt*16+g*4+r][nt*16+c].
// Register transpose: a2[jt][kh] = pack8(acc1[2kh][jt], acc1[2kh+1][jt]) is EXACTLY
//   the A-fragment of T^T (row=jt*16+c, k-slots via the same kappa map).
// Stage 2: Out^T = T^T @ W1^T with B = W1 rows under kappa.
//   lane(c,g) holds Out[it*16+c][jt*16+g*4+r] -> plain f32x4 store (L2 merges lines).
// ONE row per wave: 8192 waves, each wave's global loads are issued exactly once
// at wave start -> maximal loads-in-flight across the whole kernel lifetime.
__global__ __launch_bounds__(256) void kron2_kernel(
    const float* __restrict__ data, const float* __restrict__ W1,
    const float* __restrict__ W2, float* __restrict__ out)
{
    const int lane = threadIdx.x & 63;
    const int c    = lane & 15;
    const int g    = lane >> 4;

    const int n = (int)((blockIdx.x * blockDim.x + threadIdx.x) >> 6);
    const float* X = data + (size_t)n * 4096;

    // ---- stage-1 A: X fragments under kappa, direct from global (issue first) ----
    s16x8 xa[4][2];
    #pragma unroll
    for (int mt = 0; mt < 4; ++mt) {
        xa[mt][0] = load_frag_k(X, mt * 16 + c, 0,  g);
        xa[mt][1] = load_frag_k(X, mt * 16 + c, 32, g);
    }

    // Weight fragments (L2-hot after the first few blocks).
    s16x8 w2f[4][2], w1f[4][2];
    #pragma unroll
    for (int t = 0; t < 4; ++t)
      #pragma unroll
      for (int kh = 0; kh < 2; ++kh) {
        w2f[t][kh] = load_frag_k(W2, t * 16 + c, kh * 32, g);
        w1f[t][kh] = load_frag_k(W1, t * 16 + c, kh * 32, g);
      }

    // ---- stage 1: T = X @ W2^T ----
    f32x4 acc1[4][4];
    #pragma unroll
    for (int mt = 0; mt < 4; ++mt)
      #pragma unroll
      for (int nt = 0; nt < 4; ++nt) {
        f32x4 a = {0.f, 0.f, 0.f, 0.f};
        a = mfma_bf16(xa[mt][0], w2f[nt][0], a);
        a = mfma_bf16(xa[mt][1], w2f[nt][1], a);
        acc1[mt][nt] = a;
      }

    // ---- register transpose: A-fragments of T^T via kappa ----
    s16x8 a2[4][2];
    #pragma unroll
    for (int jt = 0; jt < 4; ++jt) {
        a2[jt][0] = pack8(acc1[0][jt], acc1[1][jt]);
        a2[jt][1] = pack8(acc1[2][jt], acc1[3][jt]);
    }

    // ---- stage 2: Out^T = T^T @ W1^T ; f32x4 stores ----
    #pragma unroll
    for (int it = 0; it < 4; ++it) {
        float* O = out + (size_t)n * 4096 + (it * 16 + c) * 64;
        #pragma unroll
        for (int jt = 0; jt < 4; ++jt) {
            f32x4 a = {0.f, 0.f, 0.f, 0.f};
            a = mfma_bf16(a2[jt][0], w1f[it][0], a);
            a = mfma_bf16(a2[jt][1], w1f[it][1], a);
            *reinterpret_cast<f32x4*>(O + jt * 16 + g * 4) = a;
        }
    }
}

extern "C" void kernel_launch(void* const* d_in, const int* in_sizes, int n_in,
                              void* d_out, int out_size, void* d_ws, size_t ws_size,
                              hipStream_t stream) {
    const float* data = (const float*)d_in[0];
    const float* W1   = (const float*)d_in[1];
    const float* W2   = (const float*)d_in[2];
    float* out        = (float*)d_out;
    dim3 grid(NROWS / 4), block(256);   // 8192 waves, 1 row per wave
    hipLaunchKernelGGL(kron2_kernel, grid, block, 0, stream, data, W1, W2, out);
}

// Round 5
// 57.983 us; speedup vs baseline: 1.1592x; 1.1592x over previous
//
#include <hip/hip_runtime.h>
#include <hip/hip_bf16.h>

typedef float  f32x4 __attribute__((ext_vector_type(4)));
typedef short  s16x8 __attribute__((ext_vector_type(8)));
typedef __bf16 b16x8 __attribute__((ext_vector_type(8)));
typedef __bf16 b16x2 __attribute__((ext_vector_type(2)));

#define NROWS 8192
#define ROWP  88   // LDS pitch in shorts; 176 B = 44 dwords -> max 2-way bank aliasing

__device__ __forceinline__ f32x4 mfma_bf16(s16x8 a, s16x8 b, f32x4 c) {
    return __builtin_amdgcn_mfma_f32_16x16x32_bf16(
        __builtin_bit_cast(b16x8, a), __builtin_bit_cast(b16x8, b), c, 0, 0, 0);
}

__device__ __forceinline__ short f2b(float f) {
    return __builtin_bit_cast(short, (__bf16)f);
}

__device__ __forceinline__ s16x8 pack8(f32x4 a, f32x4 b) {
    s16x8 r;
    r[0] = f2b(a[0]); r[1] = f2b(a[1]); r[2] = f2b(a[2]); r[3] = f2b(a[3]);
    r[4] = f2b(b[0]); r[5] = f2b(b[1]); r[6] = f2b(b[2]); r[7] = f2b(b[3]);
    return r;
}

__device__ __forceinline__ int2 pack4(f32x4 v) {
    b16x2 p0; p0[0] = (__bf16)v[0]; p0[1] = (__bf16)v[1];
    b16x2 p1; p1[0] = (__bf16)v[2]; p1[1] = (__bf16)v[3];
    int2 r;
    r.x = __builtin_bit_cast(int, p0);
    r.y = __builtin_bit_cast(int, p1);
    return r;
}

// id8 k-map: slot s <- col colbase + s (8 contiguous)
__device__ __forceinline__ s16x8 load_frag_id(const float* __restrict__ mat, int row, int colbase) {
    const float* p = mat + row * 64 + colbase;
    return pack8(*reinterpret_cast<const f32x4*>(p), *reinterpret_cast<const f32x4*>(p + 4));
}

// kappa k-map: slot s<4 <- col cb + g*4 + s ; slot s>=4 <- col cb + 16 + g*4 + (s-4)
__device__ __forceinline__ s16x8 load_frag_k(const float* __restrict__ mat, int row, int cb, int g) {
    const float* p = mat + row * 64 + cb + g * 4;
    return pack8(*reinterpret_cast<const f32x4*>(p), *reinterpret_cast<const f32x4*>(p + 16));
}

// Per row n: Out = W1 * X * W2^T (all 64x64).
// X path (NEW): fully-coalesced global loads (16 x 1KB lane-contiguous dwordx4),
//   f32->bf16 in regs, staged to per-wave padded LDS (pitch ROWP), fragments read
//   with id8 map (2-way-max bank aliasing).
// Stage 1: T = X @ W2^T (id8 map both sides). acc1[mt][nt]: lane(c,g) holds
//   T[mt*16+g*4+r][nt*16+c].
// Register transpose: a2[jt][*] = A-fragments of T^T under the kappa map.
// Stage 2: Out^T = T^T @ W1^T (kappa map both sides); f32x4 direct stores.
__global__ __launch_bounds__(256) void kron2_kernel(
    const float* __restrict__ data, const float* __restrict__ W1,
    const float* __restrict__ W2, float* __restrict__ out)
{
    __shared__ short lds[4][64][ROWP];
    const int lane = threadIdx.x & 63;
    const int wv   = threadIdx.x >> 6;
    const int c    = lane & 15;
    const int g    = lane >> 4;
    const int cf   = lane & 15;   // staging: column quad
    const int rg   = lane >> 4;   // staging: row within 4-row group
    short (*XT)[ROWP] = lds[wv];

    // Weight fragments, once per wave (amortized over 2 rows).
    s16x8 w2f[4][2], w1f[4][2];
    #pragma unroll
    for (int t = 0; t < 4; ++t)
      #pragma unroll
      for (int kh = 0; kh < 2; ++kh) {
        w2f[t][kh] = load_frag_id(W2, t * 16 + c, kh * 32 + g * 8);  // id8
        w1f[t][kh] = load_frag_k (W1, t * 16 + c, kh * 32, g);       // kappa
      }

    const int w = (int)((blockIdx.x * blockDim.x + threadIdx.x) >> 6);

    #pragma unroll
    for (int rr = 0; rr < 2; ++rr) {
        const int n = w * 2 + rr;               // consecutive rows per wave
        const float* X = data + (size_t)n * 4096;

        // ---- coalesced stage: 2 chunks x 8 instructions x 1KB contiguous ----
        #pragma unroll
        for (int h = 0; h < 2; ++h) {
            f32x4 v[8];
            #pragma unroll
            for (int i = 0; i < 8; ++i)
                v[i] = *reinterpret_cast<const f32x4*>(X + (h * 8 + i) * 256 + lane * 4);
            #pragma unroll
            for (int i = 0; i < 8; ++i) {
                const int row = (h * 8 + i) * 4 + rg;
                *reinterpret_cast<int2*>(&XT[row][cf * 4]) = pack4(v[i]);
            }
        }

        // ---- fragments from LDS (id8 map) ----
        s16x8 xa[4][2];
        #pragma unroll
        for (int mt = 0; mt < 4; ++mt)
          #pragma unroll
          for (int kh = 0; kh < 2; ++kh)
            xa[mt][kh] = *reinterpret_cast<const s16x8*>(&XT[mt * 16 + c][kh * 32 + g * 8]);

        // ---- stage 1: T = X @ W2^T ----
        f32x4 acc1[4][4];
        #pragma unroll
        for (int mt = 0; mt < 4; ++mt)
          #pragma unroll
          for (int nt = 0; nt < 4; ++nt) {
            f32x4 a = {0.f, 0.f, 0.f, 0.f};
            a = mfma_bf16(xa[mt][0], w2f[nt][0], a);
            a = mfma_bf16(xa[mt][1], w2f[nt][1], a);
            acc1[mt][nt] = a;
          }

        // ---- register transpose: A-fragments of T^T via kappa ----
        s16x8 a2[4][2];
        #pragma unroll
        for (int jt = 0; jt < 4; ++jt) {
            a2[jt][0] = pack8(acc1[0][jt], acc1[1][jt]);
            a2[jt][1] = pack8(acc1[2][jt], acc1[3][jt]);
        }

        // ---- stage 2: Out^T = T^T @ W1^T ; direct f32x4 stores ----
        #pragma unroll
        for (int it = 0; it < 4; ++it) {
            float* O = out + (size_t)n * 4096 + (it * 16 + c) * 64;
            #pragma unroll
            for (int jt = 0; jt < 4; ++jt) {
                f32x4 a = {0.f, 0.f, 0.f, 0.f};
                a = mfma_bf16(a2[jt][0], w1f[it][0], a);
                a = mfma_bf16(a2[jt][1], w1f[it][1], a);
                *reinterpret_cast<f32x4*>(O + jt * 16 + g * 4) = a;
            }
        }
    }
}

extern "C" void kernel_launch(void* const* d_in, const int* in_sizes, int n_in,
                              void* d_out, int out_size, void* d_ws, size_t ws_size,
                              hipStream_t stream) {
    const float* data = (const float*)d_in[0];
    const float* W1   = (const float*)d_in[1];
    const float* W2   = (const float*)d_in[2];
    float* out        = (float*)d_out;
    dim3 grid(NROWS / 8), block(256);   // 4096 waves x 2 consecutive rows
    hipLaunchKernelGGL(kron2_kernel, grid, block, 0, stream, data, W1, W2, out);
}

// Round 6
// 50.365 us; speedup vs baseline: 1.3346x; 1.1513x over previous
//
#include <hip/hip_runtime.h>
#include <hip/hip_bf16.h>

typedef float  f32x4 __attribute__((ext_vector_type(4)));
typedef short  s16x8 __attribute__((ext_vector_type(8)));
typedef __bf16 b16x8 __attribute__((ext_vector_type(8)));
typedef __bf16 b16x2 __attribute__((ext_vector_type(2)));

#define NROWS  8192
#define ROWP   72      // X staging pitch (shorts); bank-optimal for id8 b128 reads
#define WBYTES 9216    // per-wave LDS: union of X-stage (64*72*2=9216B) and O-stage (8192B)

__device__ __forceinline__ f32x4 mfma_bf16(s16x8 a, s16x8 b, f32x4 c) {
    return __builtin_amdgcn_mfma_f32_16x16x32_bf16(
        __builtin_bit_cast(b16x8, a), __builtin_bit_cast(b16x8, b), c, 0, 0, 0);
}

__device__ __forceinline__ short f2b(float f) {
    return __builtin_bit_cast(short, (__bf16)f);
}

__device__ __forceinline__ s16x8 pack8(f32x4 a, f32x4 b) {
    s16x8 r;
    r[0] = f2b(a[0]); r[1] = f2b(a[1]); r[2] = f2b(a[2]); r[3] = f2b(a[3]);
    r[4] = f2b(b[0]); r[5] = f2b(b[1]); r[6] = f2b(b[2]); r[7] = f2b(b[3]);
    return r;
}

__device__ __forceinline__ int2 pack4(f32x4 v) {
    b16x2 p0; p0[0] = (__bf16)v[0]; p0[1] = (__bf16)v[1];
    b16x2 p1; p1[0] = (__bf16)v[2]; p1[1] = (__bf16)v[3];
    int2 r;
    r.x = __builtin_bit_cast(int, p0);
    r.y = __builtin_bit_cast(int, p1);
    return r;
}

// id8 k-map: slot s <- col colbase + s
__device__ __forceinline__ s16x8 load_frag_id(const float* __restrict__ mat, int row, int colbase) {
    const float* p = mat + row * 64 + colbase;
    return pack8(*reinterpret_cast<const f32x4*>(p), *reinterpret_cast<const f32x4*>(p + 4));
}

// kappa k-map: slot s<4 <- col cb + g*4 + s ; slot s>=4 <- col cb + 16 + g*4 + (s-4)
__device__ __forceinline__ s16x8 load_frag_k(const float* __restrict__ mat, int row, int cb, int g) {
    const float* p = mat + row * 64 + cb + g * 4;
    return pack8(*reinterpret_cast<const f32x4*>(p), *reinterpret_cast<const f32x4*>(p + 16));
}

// Per row n: Out = W1 * X * W2^T (all 64x64).
// X path: coalesced 16x1KB loads -> bf16 -> LDS (pitch ROWP) -> id8 fragments.
// Stage 1: T = X @ W2^T (id8).  Register transpose -> A-frags of T^T (kappa).
// Stage 2: Out^T = T^T @ W1^T (kappa).  NEW: accumulators round-trip through a
// swizzled LDS tile (reusing the X buffer) so global stores are 16 x 1KB
// lane-contiguous instructions per row instead of 16 x (16x64B-segment) ones.
// Swizzle: physical col = col ^ (4*(row&15)) -> both ds_write (8 dw/bank) and
// lane-contiguous ds_read are bank-optimal.
__global__ __launch_bounds__(256) void kron2_kernel(
    const float* __restrict__ data, const float* __restrict__ W1,
    const float* __restrict__ W2, float* __restrict__ out)
{
    __shared__ __align__(16) char smem[4][WBYTES];
    const int lane = threadIdx.x & 63;
    const int wv   = threadIdx.x >> 6;
    const int c    = lane & 15;
    const int g    = lane >> 4;
    short (*XT)[ROWP] = reinterpret_cast<short(*)[ROWP]>(&smem[wv][0]);
    float* OL         = reinterpret_cast<float*>(&smem[wv][0]);

    // Weight fragments, once per wave (amortized over 2 rows).
    s16x8 w2f[4][2], w1f[4][2];
    #pragma unroll
    for (int t = 0; t < 4; ++t)
      #pragma unroll
      for (int kh = 0; kh < 2; ++kh) {
        w2f[t][kh] = load_frag_id(W2, t * 16 + c, kh * 32 + g * 8);  // id8
        w1f[t][kh] = load_frag_k (W1, t * 16 + c, kh * 32, g);       // kappa
      }

    const int w = (int)((blockIdx.x * blockDim.x + threadIdx.x) >> 6);

    #pragma unroll
    for (int rr = 0; rr < 2; ++rr) {
        const int n = w * 2 + rr;
        const float* X = data + (size_t)n * 4096;

        // ---- coalesced X stage: 16 x 1KB lane-contiguous loads ----
        #pragma unroll
        for (int h = 0; h < 2; ++h) {
            f32x4 v[8];
            #pragma unroll
            for (int i = 0; i < 8; ++i)
                v[i] = *reinterpret_cast<const f32x4*>(X + (h * 8 + i) * 256 + lane * 4);
            #pragma unroll
            for (int i = 0; i < 8; ++i) {
                const int row = (h * 8 + i) * 4 + g;
                *reinterpret_cast<int2*>(&XT[row][c * 4]) = pack4(v[i]);
            }
        }

        // ---- X fragments from LDS (id8 map) ----
        s16x8 xa[4][2];
        #pragma unroll
        for (int mt = 0; mt < 4; ++mt)
          #pragma unroll
          for (int kh = 0; kh < 2; ++kh)
            xa[mt][kh] = *reinterpret_cast<const s16x8*>(&XT[mt * 16 + c][kh * 32 + g * 8]);

        // ---- stage 1: T = X @ W2^T ----
        f32x4 acc1[4][4];
        #pragma unroll
        for (int mt = 0; mt < 4; ++mt)
          #pragma unroll
          for (int nt = 0; nt < 4; ++nt) {
            f32x4 a = {0.f, 0.f, 0.f, 0.f};
            a = mfma_bf16(xa[mt][0], w2f[nt][0], a);
            a = mfma_bf16(xa[mt][1], w2f[nt][1], a);
            acc1[mt][nt] = a;
          }

        // ---- register transpose: A-fragments of T^T via kappa ----
        s16x8 a2[4][2];
        #pragma unroll
        for (int jt = 0; jt < 4; ++jt) {
            a2[jt][0] = pack8(acc1[0][jt], acc1[1][jt]);
            a2[jt][1] = pack8(acc1[2][jt], acc1[3][jt]);
        }

        // ---- stage 2 + coalesced store, in 32-row halves through LDS ----
        #pragma unroll
        for (int h2 = 0; h2 < 2; ++h2) {
            // compute + swizzled LDS write (X buffer is dead by now; reuse as OL)
            #pragma unroll
            for (int q = 0; q < 2; ++q) {
                const int it = h2 * 2 + q;
                #pragma unroll
                for (int jt = 0; jt < 4; ++jt) {
                    f32x4 a = {0.f, 0.f, 0.f, 0.f};
                    a = mfma_bf16(a2[jt][0], w1f[it][0], a);
                    a = mfma_bf16(a2[jt][1], w1f[it][1], a);
                    // logical: OL[row=q*16+c][col=jt*16+g*4], swizzled
                    const int prow = q * 16 + c;
                    const int pcol = (jt * 16 + g * 4) ^ (c * 4);
                    *reinterpret_cast<f32x4*>(&OL[prow * 64 + pcol]) = a;
                }
            }
            // lane-contiguous read-back + 1KB global stores
            #pragma unroll
            for (int s = 0; s < 8; ++s) {
                const int prow = s * 4 + (lane >> 4);
                const int pcol = ((lane & 15) * 4) ^ ((prow & 15) * 4);
                f32x4 v = *reinterpret_cast<const f32x4*>(&OL[prow * 64 + pcol]);
                *reinterpret_cast<f32x4*>(
                    out + (size_t)n * 4096 + h2 * 2048 + s * 256 + lane * 4) = v;
            }
            // fence compiler reordering across the OL reuse (HW LDS is in-order per wave)
            asm volatile("" ::: "memory");
            __builtin_amdgcn_sched_barrier(0);
        }
        asm volatile("" ::: "memory");
        __builtin_amdgcn_sched_barrier(0);
    }
}

extern "C" void kernel_launch(void* const* d_in, const int* in_sizes, int n_in,
                              void* d_out, int out_size, void* d_ws, size_t ws_size,
                              hipStream_t stream) {
    const float* data = (const float*)d_in[0];
    const float* W1   = (const float*)d_in[1];
    const float* W2   = (const float*)d_in[2];
    float* out        = (float*)d_out;
    dim3 grid(NROWS / 8), block(256);   // 4096 waves x 2 consecutive rows
    hipLaunchKernelGGL(kron2_kernel, grid, block, 0, stream, data, W1, W2, out);
}